// Round 1
// baseline (290.937 us; speedup 1.0000x reference)
//
#include <hip/hip_runtime.h>

#define N_NODES 4096
#define FIN     512
#define FOUT    256

typedef __attribute__((ext_vector_type(8))) short bf16x8s;   // 8 bf16 in 4 VGPRs (guide §3)
typedef __attribute__((ext_vector_type(4))) float f32x4;
typedef __attribute__((ext_vector_type(8))) unsigned short u16x8;

__device__ inline unsigned short f2b(float f) {
    union { float f; unsigned int u; } v; v.f = f;
    unsigned int r = v.u + 0x7fffu + ((v.u >> 16) & 1u);   // RTNE
    return (unsigned short)(r >> 16);
}
__device__ inline float b2f(unsigned short s) {
    union { unsigned int u; float f; } v; v.u = ((unsigned int)s) << 16;
    return v.f;
}

// ---------------------------------------------------------------------------
// Kernel 1: WhT[b][n][i] = (h @ W_b)[i][n]  (bf16, transposed store)
// tiles: 64 rows(i) x 64 cols(n), K-loop 32; block 256 = 4 waves, wave w owns
// rows [w*16, w*16+16), acc 4 n-tiles.
// ---------------------------------------------------------------------------
__global__ __launch_bounds__(256) void wh_gemm_kernel(
    const float* __restrict__ h, const float* __restrict__ Wn,
    const float* __restrict__ Wd, unsigned short* __restrict__ WhT)
{
    __shared__ unsigned short smem[64 * 64];   // a:[0,2048) 64r x 32k ; b:[2048,4096) 64n x 32k ; reused as c[n][i]
    unsigned short* a_lds = smem;
    unsigned short* b_lds = smem + 2048;

    const int t  = threadIdx.x;
    const int lane = t & 63, w = t >> 6;
    const int q = lane >> 4, ln = lane & 15;
    const int i0 = blockIdx.x * 64;
    const int n0 = blockIdx.y * 64;
    const int b  = blockIdx.z;
    const float* W = b ? Wd : Wn;

    const int ar = t >> 2, ac = (t & 3) * 8;   // A staging: row, col8
    const int bk = t >> 3, bn = (t & 7) * 8;   // B staging: k, n8

    f32x4 acc[4];
    #pragma unroll
    for (int i = 0; i < 4; ++i) acc[i] = (f32x4){0.f, 0.f, 0.f, 0.f};

    for (int kt = 0; kt < 16; ++kt) {
        const int k0 = kt * 32;
        __syncthreads();
        {   // stage A tile (h rows, bf16)
            const float* src = h + (size_t)(i0 + ar) * FIN + k0 + ac;
            float4 f0 = *(const float4*)src;
            float4 f1 = *(const float4*)(src + 4);
            u16x8 o;
            o[0]=f2b(f0.x); o[1]=f2b(f0.y); o[2]=f2b(f0.z); o[3]=f2b(f0.w);
            o[4]=f2b(f1.x); o[5]=f2b(f1.y); o[6]=f2b(f1.z); o[7]=f2b(f1.w);
            *(u16x8*)&a_lds[ar * 32 + ac] = o;
        }
        {   // stage B tile transposed: b_lds[n][k]
            const float* src = W + (size_t)(k0 + bk) * FOUT + n0 + bn;
            float4 f0 = *(const float4*)src;
            float4 f1 = *(const float4*)(src + 4);
            float fv[8] = {f0.x, f0.y, f0.z, f0.w, f1.x, f1.y, f1.z, f1.w};
            #pragma unroll
            for (int jj = 0; jj < 8; ++jj) b_lds[(bn + jj) * 32 + bk] = f2b(fv[jj]);
        }
        __syncthreads();
        bf16x8s af = *(const bf16x8s*)&a_lds[(w * 16 + ln) * 32 + q * 8];
        #pragma unroll
        for (int nt = 0; nt < 4; ++nt) {
            bf16x8s bfv = *(const bf16x8s*)&b_lds[(nt * 16 + ln) * 32 + q * 8];
            acc[nt] = __builtin_amdgcn_mfma_f32_16x16x32_bf16(af, bfv, acc[nt], 0, 0, 0);
        }
    }
    __syncthreads();
    // transpose C into smem as c[n_local][i_local]
    #pragma unroll
    for (int nt = 0; nt < 4; ++nt)
        #pragma unroll
        for (int r = 0; r < 4; ++r) {
            int row = w * 16 + q * 4 + r;     // i_local
            int col = nt * 16 + ln;           // n_local
            smem[col * 64 + row] = f2b(acc[nt][r]);
        }
    __syncthreads();
    {   // coalesced-ish store of WhT[n][i] runs (32B per thread)
        const int nl = t >> 2, is = (t & 3) * 16;
        unsigned short* dst = WhT + ((size_t)b << 20) + (size_t)(n0 + nl) * N_NODES + i0 + is;
        uint4 v0 = *(uint4*)&smem[nl * 64 + is];
        uint4 v1 = *(uint4*)&smem[nl * 64 + is + 8];
        *(uint4*)dst = v0;
        *(uint4*)(dst + 8) = v1;
    }
}

// ---------------------------------------------------------------------------
// Kernel 2: s1[b][i] = sum_n WhT[b][n][i]*a1[n]; s2 likewise (shared WhT read)
// ---------------------------------------------------------------------------
__global__ __launch_bounds__(256) void svec_kernel(
    const unsigned short* __restrict__ WhT,
    const float* __restrict__ a1n, const float* __restrict__ a2n,
    const float* __restrict__ a1d, const float* __restrict__ a2d,
    float* __restrict__ s1, float* __restrict__ s2)
{
    const int b = blockIdx.y;
    const int i = blockIdx.x * 256 + threadIdx.x;
    const float* a1 = b ? a1d : a1n;
    const float* a2 = b ? a2d : a2n;
    const unsigned short* wb = WhT + ((size_t)b << 20) + i;
    float v1 = 0.f, v2 = 0.f;
    #pragma unroll 8
    for (int n = 0; n < FOUT; ++n) {
        float wv = b2f(wb[(size_t)n * N_NODES]);
        v1 += wv * a1[n];
        v2 += wv * a2[n];
    }
    s1[b * N_NODES + i] = v1;
    s2[b * N_NODES + i] = v2;
}

// ---------------------------------------------------------------------------
// Kernel 3: fused masked-softmax attention, unnormalized accumulation.
// Block: 32 rows, j-tiles of 64. num via MFMA (P bf16 @ WhT bf16), den via
// width-8 shuffle reduce. Epilogue: elu(num/den) -> outp[branch].
// ---------------------------------------------------------------------------
__global__ __launch_bounds__(256) void attn_kernel(
    const int* __restrict__ adj_n, const int* __restrict__ adj_d,
    const unsigned short* __restrict__ WhT,
    const float* __restrict__ s1, const float* __restrict__ s2,
    float* __restrict__ outp)
{
    __shared__ unsigned short wht_lds[256 * 64];  // [n][k] bf16, 32 KB
    __shared__ unsigned short p_lds[32 * 64];     // [m][k] bf16, 4 KB
    __shared__ float den_lds[32];

    const int t = threadIdx.x;
    const int lane = t & 63, w = t >> 6;
    const int q = lane >> 4, ln = lane & 15;
    const int b  = blockIdx.y;
    const int i0 = blockIdx.x * 32;

    const int* adj = b ? adj_d : adj_n;
    const unsigned short* whtB = WhT + ((size_t)b << 20);
    const float* s1b = s1 + b * N_NODES;
    const float* s2b = s2 + b * N_NODES;

    const int pr = t >> 3;             // P row 0..31
    const int pc = (t & 7) * 8;        // P col start
    const float s1v = s1b[i0 + pr];
    const size_t adj_row = (size_t)(i0 + pr) * N_NODES + pc;

    if (t < 32) den_lds[t] = 0.f;

    f32x4 acc[2][4];
    #pragma unroll
    for (int mt = 0; mt < 2; ++mt)
        #pragma unroll
        for (int nt = 0; nt < 4; ++nt) acc[mt][nt] = (f32x4){0.f, 0.f, 0.f, 0.f};

    for (int j0 = 0; j0 < N_NODES; j0 += 64) {
        __syncthreads();
        // issue register loads first so their waitcnt doesn't drain the glds queue
        int4 av0 = *(const int4*)&adj[adj_row + j0];
        int4 av1 = *(const int4*)&adj[adj_row + j0 + 4];
        float4 sv0 = *(const float4*)&s2b[j0 + pc];
        float4 sv1 = *(const float4*)&s2b[j0 + pc + 4];
        // async stage WhT tile: 2048 16B chunks, 8 per thread, dest = base + lane*16
        #pragma unroll
        for (int it = 0; it < 8; ++it) {
            int chunk = it * 256 + t;
            int n = chunk >> 3, kc = chunk & 7;
            const unsigned short* g = whtB + (size_t)n * N_NODES + j0 + kc * 8;
            unsigned short* l = &wht_lds[(it * 256 + w * 64) * 8];
            __builtin_amdgcn_global_load_lds(
                (const __attribute__((address_space(1))) void*)g,
                (__attribute__((address_space(3))) void*)l, 16, 0, 0);
        }
        int   avi[8] = {av0.x, av0.y, av0.z, av0.w, av1.x, av1.y, av1.z, av1.w};
        float svf[8] = {sv0.x, sv0.y, sv0.z, sv0.w, sv1.x, sv1.y, sv1.z, sv1.w};
        float den_part = 0.f;
        u16x8 pk;
        #pragma unroll
        for (int jj = 0; jj < 8; ++jj) {
            float x = s1v + svf[jj];
            float lr = fmaxf(x, 0.2f * x);            // leaky_relu
            float p = (avi[jj] > 0) ? __expf(lr) : 0.f;
            den_part += p;
            pk[jj] = f2b(p);
        }
        den_part += __shfl_down(den_part, 4, 8);
        den_part += __shfl_down(den_part, 2, 8);
        den_part += __shfl_down(den_part, 1, 8);
        if ((t & 7) == 0) den_lds[pr] += den_part;
        *(u16x8*)&p_lds[pr * 64 + pc] = pk;
        __syncthreads();   // drains glds (vmcnt) + LDS writes
        #pragma unroll
        for (int ks = 0; ks < 2; ++ks) {
            bf16x8s a0 = *(const bf16x8s*)&p_lds[ln * 64 + ks * 32 + q * 8];
            bf16x8s a1f = *(const bf16x8s*)&p_lds[(16 + ln) * 64 + ks * 32 + q * 8];
            #pragma unroll
            for (int nt = 0; nt < 4; ++nt) {
                bf16x8s bfv = *(const bf16x8s*)&wht_lds[(w * 64 + nt * 16 + ln) * 64 + ks * 32 + q * 8];
                acc[0][nt] = __builtin_amdgcn_mfma_f32_16x16x32_bf16(a0, bfv, acc[0][nt], 0, 0, 0);
                acc[1][nt] = __builtin_amdgcn_mfma_f32_16x16x32_bf16(a1f, bfv, acc[1][nt], 0, 0, 0);
            }
        }
    }
    // epilogue: out = elu(num/den); den writes were before last barrier -> visible
    #pragma unroll
    for (int mt = 0; mt < 2; ++mt)
        #pragma unroll
        for (int r = 0; r < 4; ++r) {
            int row = mt * 16 + q * 4 + r;
            float inv = 1.0f / den_lds[row];
            #pragma unroll
            for (int nt = 0; nt < 4; ++nt) {
                float o = acc[mt][nt][r] * inv;
                o = (o > 0.f) ? o : expm1f(o);        // elu, alpha=1
                outp[((size_t)b * N_NODES + i0 + row) * FOUT + w * 64 + nt * 16 + ln] = o;
            }
        }
}

// ---------------------------------------------------------------------------
// Kernel 4: out = outp[0] + outp[1]
// ---------------------------------------------------------------------------
__global__ __launch_bounds__(256) void combine_kernel(
    const float* __restrict__ outp, float* __restrict__ out)
{
    int idx = (blockIdx.x * 256 + threadIdx.x) * 4;
    float4 v0 = *(const float4*)&outp[idx];
    float4 v1 = *(const float4*)&outp[(1u << 20) + idx];
    float4 o;
    o.x = v0.x + v1.x; o.y = v0.y + v1.y; o.z = v0.z + v1.z; o.w = v0.w + v1.w;
    *(float4*)&out[idx] = o;
}

extern "C" void kernel_launch(void* const* d_in, const int* in_sizes, int n_in,
                              void* d_out, int out_size, void* d_ws, size_t ws_size,
                              hipStream_t stream) {
    const float* h    = (const float*)d_in[0];
    const int*   adjn = (const int*)d_in[1];
    const int*   adjd = (const int*)d_in[2];
    // d_in[3] = G_nd (unused by reference output)
    const float* Wn   = (const float*)d_in[4];
    const float* a1n  = (const float*)d_in[5];
    const float* a2n  = (const float*)d_in[6];
    const float* Wd   = (const float*)d_in[7];
    const float* a1d  = (const float*)d_in[8];
    const float* a2d  = (const float*)d_in[9];
    // d_in[10] = scale (unused)

    // workspace layout
    unsigned short* WhT = (unsigned short*)d_ws;                        // 2 * 1M bf16 = 4 MB
    float* outp = (float*)((char*)d_ws + (4u << 20));                   // 2 * 1M f32  = 8 MB
    float* s1   = (float*)((char*)d_ws + (12u << 20));                  // 2 * 4096 f32
    float* s2   = s1 + 2 * N_NODES;

    wh_gemm_kernel<<<dim3(64, 4, 2), 256, 0, stream>>>(h, Wn, Wd, WhT);
    svec_kernel<<<dim3(16, 2), 256, 0, stream>>>(WhT, a1n, a2n, a1d, a2d, s1, s2);
    attn_kernel<<<dim3(128, 2), 256, 0, stream>>>(adjn, adjd, WhT, s1, s2, outp);
    combine_kernel<<<1024, 256, 0, stream>>>(outp, (float*)d_out);
}

// Round 2
// 223.449 us; speedup vs baseline: 1.3020x; 1.3020x over previous
//
#include <hip/hip_runtime.h>

#define N_NODES 4096
#define FIN     512
#define FOUT    256
#define NSPLIT  4          // j-dimension splits in attn (4096/4 = 1024 per block)

typedef __attribute__((ext_vector_type(8))) short bf16x8s;
typedef __attribute__((ext_vector_type(4))) float f32x4;
typedef __attribute__((ext_vector_type(8))) unsigned short u16x8;
typedef unsigned short u16;

__device__ inline u16 f2b(float f) {
    union { float f; unsigned int u; } v; v.f = f;
    unsigned int r = v.u + 0x7fffu + ((v.u >> 16) & 1u);   // RTNE
    return (u16)(r >> 16);
}

// ---------------------------------------------------------------------------
// prep kernel (merged): blocks [0,1024): h fp32 -> hb bf16
//                       blocks [1024,1088): W_b -> WTb bf16 transposed [n][k]
//                       blocks [1088,1120): wv[v] = W_v @ a_v  (4 GEMVs, 512 ea)
// ---------------------------------------------------------------------------
__global__ __launch_bounds__(256) void prep_kernel(
    const float* __restrict__ h, const float* __restrict__ Wn,
    const float* __restrict__ Wd,
    const float* __restrict__ a1n, const float* __restrict__ a2n,
    const float* __restrict__ a1d, const float* __restrict__ a2d,
    u16* __restrict__ hb, u16* __restrict__ WTb, float* __restrict__ wv)
{
    __shared__ u16 tl[64 * 72];
    __shared__ float sa[256];
    const int t = threadIdx.x;
    const int bid = blockIdx.x;

    if (bid < 1024) {                       // h convert
        int idx = (bid * 256 + t) * 8;
        float4 f0 = *(const float4*)&h[idx];
        float4 f1 = *(const float4*)&h[idx + 4];
        u16x8 o;
        o[0]=f2b(f0.x); o[1]=f2b(f0.y); o[2]=f2b(f0.z); o[3]=f2b(f0.w);
        o[4]=f2b(f1.x); o[5]=f2b(f1.y); o[6]=f2b(f1.z); o[7]=f2b(f1.w);
        *(u16x8*)&hb[idx] = o;
    } else if (bid < 1088) {                // W transpose+convert, 64x64 tiles
        int id = bid - 1024;
        int kx = id & 7, ny = (id >> 3) & 3, b = id >> 5;
        const float* W = b ? Wd : Wn;
        int k0 = kx * 64, n0 = ny * 64;
        int kr = t >> 2, nc0 = (t & 3) * 16;
        const float* src = W + (size_t)(k0 + kr) * FOUT + n0 + nc0;
        #pragma unroll
        for (int jv = 0; jv < 4; ++jv) {
            float4 f = *(const float4*)(src + jv * 4);
            tl[(nc0 + jv * 4 + 0) * 72 + kr] = f2b(f.x);
            tl[(nc0 + jv * 4 + 1) * 72 + kr] = f2b(f.y);
            tl[(nc0 + jv * 4 + 2) * 72 + kr] = f2b(f.z);
            tl[(nc0 + jv * 4 + 3) * 72 + kr] = f2b(f.w);
        }
        __syncthreads();
        int n = t >> 2, kc0 = (t & 3) * 16;
        u16* dst = WTb + ((size_t)b << 17) + (size_t)(n0 + n) * FIN + k0 + kc0;
        *(uint4*)dst       = *(uint4*)&tl[n * 72 + kc0];
        *(uint4*)(dst + 8) = *(uint4*)&tl[n * 72 + kc0 + 8];
    } else {                                // wv[v][k] = sum_n W_v[k][n] * a_v[n]
        int id = bid - 1088;
        int kb = id & 7, v = id >> 3;
        const float* W = (v < 2) ? Wn : Wd;
        const float* a = (v == 0) ? a1n : (v == 1) ? a2n : (v == 2) ? a1d : a2d;
        sa[t] = a[t];
        __syncthreads();
        int k = kb * 64 + (t >> 2);
        int nseg = (t & 3) * 64;
        const float* wr = W + (size_t)k * FOUT + nseg;
        float sum = 0.f;
        #pragma unroll 8
        for (int j = 0; j < 64; ++j) sum += wr[j] * sa[nseg + j];
        sum += __shfl_down(sum, 2, 4);
        sum += __shfl_down(sum, 1, 4);
        if ((t & 3) == 0) wv[v * FIN + k] = sum;
    }
}

// ---------------------------------------------------------------------------
// s kernel: s1[b][i] = h[i,:] . wv[2b], s2[b][i] = h[i,:] . wv[2b+1]
// one wave per row.
// ---------------------------------------------------------------------------
__global__ __launch_bounds__(256) void s_kernel(
    const float* __restrict__ h, const float* __restrict__ wv,
    float* __restrict__ s1, float* __restrict__ s2)
{
    const int t = threadIdx.x, lane = t & 63, w = t >> 6;
    const int b = blockIdx.y;
    const int row = blockIdx.x * 4 + w;
    const float* w1 = wv + (b * 2 + 0) * FIN;
    const float* w2 = wv + (b * 2 + 1) * FIN;
    const float* hr = h + (size_t)row * FIN + lane * 8;
    float4 h0 = *(const float4*)hr, h1 = *(const float4*)(hr + 4);
    float4 p0 = *(const float4*)&w1[lane * 8], p1 = *(const float4*)&w1[lane * 8 + 4];
    float4 q0 = *(const float4*)&w2[lane * 8], q1 = *(const float4*)&w2[lane * 8 + 4];
    float d1 = h0.x*p0.x + h0.y*p0.y + h0.z*p0.z + h0.w*p0.w
             + h1.x*p1.x + h1.y*p1.y + h1.z*p1.z + h1.w*p1.w;
    float d2 = h0.x*q0.x + h0.y*q0.y + h0.z*q0.z + h0.w*q0.w
             + h1.x*q1.x + h1.y*q1.y + h1.z*q1.z + h1.w*q1.w;
    #pragma unroll
    for (int off = 32; off >= 1; off >>= 1) {
        d1 += __shfl_xor(d1, off);
        d2 += __shfl_xor(d2, off);
    }
    if (lane == 0) { s1[b * N_NODES + row] = d1; s2[b * N_NODES + row] = d2; }
}

// ---------------------------------------------------------------------------
// wh_gemm: WhT[b][n][i] = (hb @ W_b)[i][n], glds-staged, XOR-swizzled LDS.
// tile 64i x 64n, BK=64. grid (64, 4, 2).
// ---------------------------------------------------------------------------
__global__ __launch_bounds__(256) void wh_gemm_kernel(
    const u16* __restrict__ hb, const u16* __restrict__ WTb,
    u16* __restrict__ WhT)
{
    __shared__ u16 smem[8192];                // a:[0,4096) b:[4096,8192); epilogue reuse
    u16* a_lds = smem;
    u16* b_lds = smem + 4096;

    const int t = threadIdx.x, lane = t & 63, w = t >> 6;
    const int q = lane >> 4, ln = lane & 15;
    const int i0 = blockIdx.x * 64, n0 = blockIdx.y * 64, b = blockIdx.z;
    const u16* wt = WTb + ((size_t)b << 17);

    f32x4 acc[4];
    #pragma unroll
    for (int i = 0; i < 4; ++i) acc[i] = (f32x4){0.f, 0.f, 0.f, 0.f};

    for (int kt = 0; kt < 8; ++kt) {
        const int k0 = kt * 64;
        __syncthreads();
        #pragma unroll
        for (int it = 0; it < 2; ++it) {      // A: 512 chunks of 16B
            int chunk = it * 256 + t;
            int r = chunk >> 3, kc = chunk & 7;
            const u16* g = hb + (size_t)(i0 + r) * FIN + k0 + ((kc ^ (r & 7)) * 8);
            u16* l = a_lds + (it * 256 + w * 64) * 8;
            __builtin_amdgcn_global_load_lds(
                (const __attribute__((address_space(1))) void*)g,
                (__attribute__((address_space(3))) void*)l, 16, 0, 0);
        }
        #pragma unroll
        for (int it = 0; it < 2; ++it) {      // B: 512 chunks of 16B
            int chunk = it * 256 + t;
            int n = chunk >> 3, kc = chunk & 7;
            const u16* g = wt + (size_t)(n0 + n) * FIN + k0 + ((kc ^ (n & 7)) * 8);
            u16* l = b_lds + (it * 256 + w * 64) * 8;
            __builtin_amdgcn_global_load_lds(
                (const __attribute__((address_space(1))) void*)g,
                (__attribute__((address_space(3))) void*)l, 16, 0, 0);
        }
        __syncthreads();
        #pragma unroll
        for (int ks = 0; ks < 2; ++ks) {
            int sw = ((ks * 4 + q) ^ (ln & 7)) * 8;
            bf16x8s af = *(const bf16x8s*)&a_lds[(w * 16 + ln) * 64 + sw];
            #pragma unroll
            for (int nt = 0; nt < 4; ++nt) {
                bf16x8s bfv = *(const bf16x8s*)&b_lds[(nt * 16 + ln) * 64 + sw];
                acc[nt] = __builtin_amdgcn_mfma_f32_16x16x32_bf16(af, bfv, acc[nt], 0, 0, 0);
            }
        }
    }
    __syncthreads();
    // transpose C into smem as c[n_local][i_local], stride 72
    #pragma unroll
    for (int nt = 0; nt < 4; ++nt)
        #pragma unroll
        for (int r = 0; r < 4; ++r)
            smem[(nt * 16 + ln) * 72 + (w * 16 + q * 4 + r)] = f2b(acc[nt][r]);
    __syncthreads();
    {
        const int nl = t >> 2, is = (t & 3) * 16;
        u16* dst = WhT + ((size_t)b << 20) + (size_t)(n0 + nl) * N_NODES + i0 + is;
        *(uint4*)dst       = *(uint4*)&smem[nl * 72 + is];
        *(uint4*)(dst + 8) = *(uint4*)&smem[nl * 72 + is + 8];
    }
}

// ---------------------------------------------------------------------------
// attn: 32 rows x 1024-j-range per block, partial num/den accumulation.
// grid (128, NSPLIT, 2), 4 blocks/CU.
// ---------------------------------------------------------------------------
__global__ __launch_bounds__(256, 4) void attn_kernel(
    const int* __restrict__ adj_n, const int* __restrict__ adj_d,
    const u16* __restrict__ WhT,
    const float* __restrict__ s1, const float* __restrict__ s2,
    float* __restrict__ num_ws, float* __restrict__ den_ws)
{
    __shared__ u16 wht_lds[256 * 64];   // swizzled [n][kchunk^(n&7)], 32 KB
    __shared__ u16 p_lds[32 * 64];      // swizzled, 4 KB
    __shared__ float den_lds[32];

    const int t = threadIdx.x, lane = t & 63, w = t >> 6;
    const int q = lane >> 4, ln = lane & 15;
    const int b = blockIdx.z, split = blockIdx.y;
    const int i0 = blockIdx.x * 32;

    const int* adj = b ? adj_d : adj_n;
    const u16* whtB = WhT + ((size_t)b << 20);
    const float* s1b = s1 + b * N_NODES;
    const float* s2b = s2 + b * N_NODES;

    const int pr = t >> 3;              // P row 0..31
    const int cw = t & 7;               // P k-chunk 0..7
    const int pc = cw * 8;
    const float s1v = s1b[i0 + pr];
    const size_t adj_row = (size_t)(i0 + pr) * N_NODES + pc;

    if (t < 32) den_lds[t] = 0.f;

    f32x4 acc[2][4];
    #pragma unroll
    for (int mt = 0; mt < 2; ++mt)
        #pragma unroll
        for (int nt = 0; nt < 4; ++nt) acc[mt][nt] = (f32x4){0.f, 0.f, 0.f, 0.f};

    const int jbase = split * (N_NODES / NSPLIT);
    for (int jt = 0; jt < (N_NODES / NSPLIT) / 64; ++jt) {
        const int j0 = jbase + jt * 64;
        __syncthreads();
        int4 av0 = *(const int4*)&adj[adj_row + j0];
        int4 av1 = *(const int4*)&adj[adj_row + j0 + 4];
        float4 sv0 = *(const float4*)&s2b[j0 + pc];
        float4 sv1 = *(const float4*)&s2b[j0 + pc + 4];
        #pragma unroll
        for (int it = 0; it < 8; ++it) {   // stage 256n x 64j tile, swizzled fetch
            int chunk = it * 256 + t;
            int n = chunk >> 3, kc = chunk & 7;
            const u16* g = whtB + (size_t)n * N_NODES + j0 + ((kc ^ (n & 7)) * 8);
            u16* l = wht_lds + (it * 256 + w * 64) * 8;
            __builtin_amdgcn_global_load_lds(
                (const __attribute__((address_space(1))) void*)g,
                (__attribute__((address_space(3))) void*)l, 16, 0, 0);
        }
        int   avi[8] = {av0.x, av0.y, av0.z, av0.w, av1.x, av1.y, av1.z, av1.w};
        float svf[8] = {sv0.x, sv0.y, sv0.z, sv0.w, sv1.x, sv1.y, sv1.z, sv1.w};
        float den_part = 0.f;
        u16x8 pk;
        #pragma unroll
        for (int jj = 0; jj < 8; ++jj) {
            float x = s1v + svf[jj];
            float lr = fmaxf(x, 0.2f * x);
            float p = (avi[jj] > 0) ? __expf(lr) : 0.f;
            den_part += p;
            pk[jj] = f2b(p);
        }
        den_part += __shfl_down(den_part, 4, 8);
        den_part += __shfl_down(den_part, 2, 8);
        den_part += __shfl_down(den_part, 1, 8);
        if ((t & 7) == 0) den_lds[pr] += den_part;
        *(u16x8*)&p_lds[pr * 64 + ((cw ^ (pr & 7)) * 8)] = pk;
        __syncthreads();
        #pragma unroll
        for (int ks = 0; ks < 2; ++ks) {
            int sw = ((ks * 4 + q) ^ (ln & 7)) * 8;
            bf16x8s a0  = *(const bf16x8s*)&p_lds[ln * 64 + sw];
            bf16x8s a1f = *(const bf16x8s*)&p_lds[(16 + ln) * 64 + sw];
            #pragma unroll
            for (int nt = 0; nt < 4; ++nt) {
                bf16x8s bfv = *(const bf16x8s*)&wht_lds[(w * 64 + nt * 16 + ln) * 64 + sw];
                acc[0][nt] = __builtin_amdgcn_mfma_f32_16x16x32_bf16(a0,  bfv, acc[0][nt], 0, 0, 0);
                acc[1][nt] = __builtin_amdgcn_mfma_f32_16x16x32_bf16(a1f, bfv, acc[1][nt], 0, 0, 0);
            }
        }
    }
    // store partials (no normalization here)
    const size_t pbase = (size_t)(b * NSPLIT + split) * N_NODES;
    #pragma unroll
    for (int mt = 0; mt < 2; ++mt)
        #pragma unroll
        for (int r = 0; r < 4; ++r) {
            int row = mt * 16 + q * 4 + r;
            #pragma unroll
            for (int nt = 0; nt < 4; ++nt)
                num_ws[(pbase + i0 + row) * FOUT + w * 64 + nt * 16 + ln] = acc[mt][nt][r];
        }
    if (t < 32) den_ws[pbase + i0 + t] = den_lds[t];
}

// ---------------------------------------------------------------------------
// reduce: sum splits, elu(num/den), merge branches.
// ---------------------------------------------------------------------------
__global__ __launch_bounds__(256) void reduce_kernel(
    const float* __restrict__ num_ws, const float* __restrict__ den_ws,
    float* __restrict__ out)
{
    int gid = blockIdx.x * 256 + threadIdx.x;
    int i = gid >> 6;
    int f4 = (gid & 63) * 4;
    float4 o = {0.f, 0.f, 0.f, 0.f};
    #pragma unroll
    for (int b = 0; b < 2; ++b) {
        float4 num = {0.f, 0.f, 0.f, 0.f};
        float den = 0.f;
        #pragma unroll
        for (int s = 0; s < NSPLIT; ++s) {
            const float4 v = *(const float4*)&num_ws[((size_t)(b * NSPLIT + s) * N_NODES + i) * FOUT + f4];
            num.x += v.x; num.y += v.y; num.z += v.z; num.w += v.w;
            den += den_ws[(size_t)(b * NSPLIT + s) * N_NODES + i];
        }
        float inv = 1.0f / den;
        float e0 = num.x * inv, e1 = num.y * inv, e2 = num.z * inv, e3 = num.w * inv;
        o.x += (e0 > 0.f) ? e0 : expm1f(e0);
        o.y += (e1 > 0.f) ? e1 : expm1f(e1);
        o.z += (e2 > 0.f) ? e2 : expm1f(e2);
        o.w += (e3 > 0.f) ? e3 : expm1f(e3);
    }
    *(float4*)&out[(size_t)i * FOUT + f4] = o;
}

extern "C" void kernel_launch(void* const* d_in, const int* in_sizes, int n_in,
                              void* d_out, int out_size, void* d_ws, size_t ws_size,
                              hipStream_t stream) {
    const float* h    = (const float*)d_in[0];
    const int*   adjn = (const int*)d_in[1];
    const int*   adjd = (const int*)d_in[2];
    const float* Wn   = (const float*)d_in[4];
    const float* a1n  = (const float*)d_in[5];
    const float* a2n  = (const float*)d_in[6];
    const float* Wd   = (const float*)d_in[7];
    const float* a1d  = (const float*)d_in[8];
    const float* a2d  = (const float*)d_in[9];

    char* ws = (char*)d_ws;
    u16*   hb   = (u16*)ws;                                  // 4 MB
    u16*   WhT  = (u16*)(ws + ((size_t)4 << 20));            // 4 MB
    u16*   WTb  = (u16*)(ws + ((size_t)8 << 20));            // 0.5 MB
    float* wv   = (float*)(ws + ((size_t)8 << 20) + (512u << 10)); // 8 KB
    float* s1   = wv + 4 * FIN;
    float* s2   = s1 + 2 * N_NODES;
    float* den  = s2 + 2 * N_NODES;                          // 2*NSPLIT*4096 f32
    float* num  = (float*)(ws + ((size_t)9 << 20));          // 2*NSPLIT*4096*256 f32 = 33.5 MB

    prep_kernel<<<1120, 256, 0, stream>>>(h, Wn, Wd, a1n, a2n, a1d, a2d, hb, WTb, wv);
    s_kernel<<<dim3(1024, 2), 256, 0, stream>>>(h, wv, s1, s2);
    wh_gemm_kernel<<<dim3(64, 4, 2), 256, 0, stream>>>(hb, WTb, WhT);
    attn_kernel<<<dim3(128, NSPLIT, 2), 256, 0, stream>>>(adjn, adjd, WhT, s1, s2, num, den);
    reduce_kernel<<<1024, 256, 0, stream>>>(num, den, (float*)d_out);
}